// Round 11
// baseline (127.574 us; speedup 1.0000x reference)
//
#include <hip/hip_runtime.h>
#include <stdint.h>

#define NA    100800
#define NIMG  8
#define TOPK  2048
#define NBLK1 99              // ceil(NA / 1024)
typedef unsigned long long u64;

// ---------------- K1: coalesced scan -> dense conf-bits + per-block LDS hist ----------------
// Row = 64 B = 4 float4s; we need quarter#1 (obj at .x) and quarter#3 (x15 at .w):
// exactly the ODD float4 indices. Thread t loads f4[2t+1] and f4[2t+513] (dense),
// __shfl_xor(1) pairs obj with x15. Even lane finalizes rows r and r+128.
__global__ __launch_bounds__(256) void k1_scan(const float* __restrict__ pred,
                                               unsigned* __restrict__ cand32,
                                               int* __restrict__ hist_blocks) {
    __shared__ int lhist[64];
    int t = threadIdx.x;
    int m = blockIdx.y;
    if (t < 64) lhist[t] = 0;
    __syncthreads();
    const float4* p4 = reinterpret_cast<const float4*>(pred + (size_t)m * NA * 16);
    int row0blk = blockIdx.x * 1024;
    for (int pass = 0; pass < 4; ++pass) {
        int row0 = row0blk + pass * 256;
        int i1 = row0 * 4 + 2 * t + 1;
        int i2 = i1 + 512;
        float4 A = make_float4(0.f, 0.f, 0.f, 0.f);
        float4 B = make_float4(0.f, 0.f, 0.f, 0.f);
        if ((i1 >> 2) < NA) A = p4[i1];
        if ((i2 >> 2) < NA) B = p4[i2];
        float aw = __shfl_xor(A.w, 1);          // x15 of row rA (valid on even lanes)
        float bw = __shfl_xor(B.w, 1);          // x15 of row rB
        if (!(t & 1)) {
            int rA = row0 + (t >> 1);
            int rB = rA + 128;
            {
                float obj = A.x, x15 = aw;
                if (rA < NA) {
                    float conf = __fmul_rn(x15, obj);   // exact ref op
                    unsigned cb = 0u;
                    if (obj > 0.5f && conf > 0.5f) {
                        cb = __float_as_uint(conf);
                        atomicAdd(&lhist[min(63, (int)((cb - 0x3F000000u) >> 17))], 1);
                    }
                    cand32[(size_t)m * NA + rA] = cb;
                }
            }
            {
                float obj = B.x, x15 = bw;
                if (rB < NA) {
                    float conf = __fmul_rn(x15, obj);
                    unsigned cb = 0u;
                    if (obj > 0.5f && conf > 0.5f) {
                        cb = __float_as_uint(conf);
                        atomicAdd(&lhist[min(63, (int)((cb - 0x3F000000u) >> 17))], 1);
                    }
                    cand32[(size_t)m * NA + rB] = cb;
                }
            }
        }
    }
    __syncthreads();
    if (t < 64) hist_blocks[((size_t)m * NBLK1 + blockIdx.x) * 64 + t] = lhist[t];
}

// ---------------- K2a: reduce per-block hists + cutoff via suffix-scan (1 wave/image) ----------------
__global__ void k2a_cutoff(const int* __restrict__ hist_blocks, int* __restrict__ cut,
                           int* __restrict__ pos) {
    int m = blockIdx.x;
    int lane = threadIdx.x;                     // 64 threads
    int h = 0;
    #pragma unroll 4
    for (int b = 0; b < NBLK1; ++b)             // coalesced: 64 consecutive ints per b
        h += hist_blocks[((size_t)m * NBLK1 + b) * 64 + lane];
    #pragma unroll
    for (int off = 1; off < 64; off <<= 1) {    // inclusive suffix sum
        int src = lane + off;
        int v = __shfl(h, src < 64 ? src : lane);
        h += (src < 64) ? v : 0;
    }
    int total  = __shfl(h, 0);
    int needed = min(total, TOPK);
    u64 bal = __ballot(h >= needed);
    int cutoff = 63 - __clzll(bal);             // highest bin with suffix >= needed
    if (lane == 0) { cut[m] = cutoff; pos[m] = 0; }
}

// ---------------- K2b: compact bin>=cutoff; ONE atomic per 1024-thread block ----------------
__global__ __launch_bounds__(1024) void k2b_compact(const unsigned* __restrict__ cand32,
                                                    const int* __restrict__ cut,
                                                    u64* __restrict__ comp,
                                                    int* __restrict__ pos) {
    __shared__ int wbase[16];
    __shared__ int sbase;
    int m = blockIdx.y;
    int i = blockIdx.x * 1024 + threadIdx.x;
    int lane = threadIdx.x & 63, wid = threadIdx.x >> 6;
    unsigned cb = (i < NA) ? cand32[(size_t)m * NA + i] : 0u;
    int c = cut[m];
    bool keep = false;
    if (cb) keep = min(63, (int)((cb - 0x3F000000u) >> 17)) >= c;
    u64 bal = __ballot(keep);
    int cnt = __popcll(bal);
    if (lane == 0) wbase[wid] = cnt;
    __syncthreads();
    if (threadIdx.x == 0) {
        int s = 0;
        #pragma unroll
        for (int w = 0; w < 16; ++w) { int v = wbase[w]; wbase[w] = s; s += v; }
        sbase = s ? atomicAdd(&pos[m], s) : 0;
    }
    __syncthreads();
    if (keep) {
        int p = sbase + wbase[wid] + (int)__popcll(bal & ((1ull << lane) - 1ull));
        if (p < 4096)
            comp[(size_t)m * 4096 + p] = ((u64)cb << 32) | (u64)(0xFFFFFFFFu - (unsigned)i);
    }
}

// ---------------- K2c: counting-rank (4096 fine bins) -> sel + staged boxes ----------------
// rbin = 4095 - (mantissa>>11): bin 0 = highest conf. Prefix-sum bin counts,
// atomic scatter within bin, then deterministic per-bin insertion sort (keys
// unique -> final order independent of atomic order). Replaces bitonic sort.
__global__ __launch_bounds__(1024) void k2c_rank(const u64* __restrict__ comp,
                                                 const int* __restrict__ pos,
                                                 const float* __restrict__ pred,
                                                 u64* __restrict__ sel,
                                                 float4* __restrict__ boxes) {
    __shared__ int fcnt[4096];
    __shared__ int fstart[4096];
    __shared__ u64 outb[4096];
    __shared__ int wsum[16];
    int m = blockIdx.x, t = threadIdx.x;
    int M = min(pos[m], 4096);
    const u64* c = comp + (size_t)m * 4096;
    #pragma unroll
    for (int r = 0; r < 4; ++r) { fcnt[t + r * 1024] = 0; outb[t + r * 1024] = 0ull; }
    __syncthreads();
    // phase 1: load keys (strided, coalesced) + fine histogram
    u64 kk[4]; int rb[4];
    #pragma unroll
    for (int r = 0; r < 4; ++r) {
        int i = t + r * 1024;
        kk[r] = 0ull; rb[r] = -1;
        if (i < M) {
            kk[r] = c[i];
            rb[r] = 4095 - (int)(((unsigned)(kk[r] >> 32) - 0x3F000000u) >> 11);
            atomicAdd(&fcnt[rb[r]], 1);
        }
    }
    __syncthreads();
    // phase 2: exclusive prefix sum over 4096 bins (thread t owns bins 4t..4t+3)
    int c0 = fcnt[4 * t], c1 = fcnt[4 * t + 1], c2 = fcnt[4 * t + 2], c3 = fcnt[4 * t + 3];
    int s = c0 + c1 + c2 + c3;
    int lane = t & 63, w = t >> 6;
    int incl = s;
    #pragma unroll
    for (int off = 1; off < 64; off <<= 1) {
        int v = __shfl_up(incl, off);
        if (lane >= off) incl += v;
    }
    if (lane == 63) wsum[w] = incl;
    __syncthreads();
    if (w == 0) {
        int v = (lane < 16) ? wsum[lane] : 0;
        #pragma unroll
        for (int off = 1; off < 16; off <<= 1) {
            int u = __shfl_up(v, off);
            if (lane >= off) v += u;
        }
        if (lane < 16) wsum[lane] = v;     // inclusive wave sums
    }
    __syncthreads();
    int base = (w > 0 ? wsum[w - 1] : 0) + (incl - s);
    fstart[4 * t]     = base;
    fstart[4 * t + 1] = base + c0;
    fstart[4 * t + 2] = base + c0 + c1;
    fstart[4 * t + 3] = base + c0 + c1 + c2;
    __syncthreads();
    // phase 3: scatter (slot order within bin arbitrary; fixed in phase 4)
    #pragma unroll
    for (int r = 0; r < 4; ++r) {
        if (rb[r] >= 0) {
            int old = atomicSub(&fcnt[rb[r]], 1);
            int slot = fstart[rb[r]] + old - 1;
            outb[slot] = kk[r];
        }
    }
    __syncthreads();
    // phase 4: deterministic cleanup — insertion-sort each bin's range desc
    #pragma unroll
    for (int r = 0; r < 4; ++r) {
        int b = t + r * 1024;
        int st = fstart[b];
        int en = (b < 4095) ? fstart[b + 1] : M;
        for (int x = st + 1; x < en; ++x) {
            u64 key = outb[x];
            int y = x - 1;
            while (y >= st && outb[y] < key) { outb[y + 1] = outb[y]; --y; }
            outb[y + 1] = key;
        }
    }
    __syncthreads();
    // phase 5: emit sel + staged xyxy boxes for top-2048
    #pragma unroll
    for (int r = 0; r < 2; ++r) {
        int i = t + r * 1024;
        u64 key = outb[i];
        sel[(size_t)m * TOPK + i] = key;
        float4 b = make_float4(0.f, 0.f, 0.f, 0.f);
        if (key) {
            unsigned idx = 0xFFFFFFFFu - (unsigned)(key & 0xFFFFFFFFull);
            const float4* rv = reinterpret_cast<const float4*>(pred + ((size_t)m * NA + idx) * 16);
            float4 v = rv[0];                   // [xc, yc, w, h]
            float hw = __fmul_rn(v.z, 0.5f), hh = __fmul_rn(v.w, 0.5f);
            b.x = __fsub_rn(v.x, hw);
            b.y = __fsub_rn(v.y, hh);
            b.z = __fadd_rn(v.x, hw);
            b.w = __fadd_rn(v.y, hh);
        }
        boxes[(size_t)m * TOPK + i] = b;
    }
}

// ---------------- K4: 2048x2048 suppression bitmask, TRANSPOSED (iou > 0.45) ----------------
// maskT[(m*32 + w)*2048 + row] : word w of row, stored word-major for coalesced
// per-word access in k5.
__global__ __launch_bounds__(1024) void k4_masks(const float4* __restrict__ boxes,
                                                 u64* __restrict__ maskT) {
    __shared__ float4 bx[TOPK];
    int m   = blockIdx.y;
    int grp = blockIdx.x;                       // 64 groups of 32 rows
    for (int i = threadIdx.x; i < TOPK; i += 1024)
        bx[i] = boxes[(size_t)m * TOPK + i];
    __syncthreads();

    int il = threadIdx.x & 31;
    int w  = threadIdx.x >> 5;
    int i  = grp * 32 + il;
    float4 b1 = bx[i];
    float a1 = __fmul_rn(__fsub_rn(b1.z, b1.x), __fsub_rn(b1.w, b1.y));
    u64 bits = 0ull;
    #pragma unroll 4
    for (int jj = 0; jj < 64; ++jj) {
        float4 b2 = bx[w * 64 + jj];
        float a2 = __fmul_rn(__fsub_rn(b2.z, b2.x), __fsub_rn(b2.w, b2.y));
        float iw = fmaxf(__fsub_rn(fminf(b1.z, b2.z), fmaxf(b1.x, b2.x)), 0.f);
        float ih = fmaxf(__fsub_rn(fminf(b1.w, b2.w), fmaxf(b1.y, b2.y)), 0.f);
        float inter = __fmul_rn(iw, ih);
        float uni   = __fsub_rn(__fadd_rn(a1, a2), inter);   // (a1+a2)-inter, ref order
        float iou   = __fdiv_rn(inter, uni);
        if (iou > 0.45f) bits |= (1ull << jj);
    }
    maskT[((size_t)m * 32 + w) * 2048 + i] = bits;
}

// ---------------- K5: greedy scan, SINGLE WAVE per image, zero barriers ----------------
// Lane's row at step blk is r = blk*64+lane. External suppression is per-lane:
//   ext = OR_pb (maskT[pb][r] & kb[pb]) != 0      (IoU symmetry)
// kb[] lives in LDS, zero-init, so the consume loop runs UNCONDITIONALLY over
// all 32 pb (future pb contribute 0) — branch-free. All 34 loads for step
// blk+1 have scan-independent addresses and are issued at step blk start into
// the other named buffer (pfA/pfB, 2-step unroll: no rotation copies, static
// register-array indexing). Single wave -> ds ops in-order, no __syncthreads.
#define K5_ISSUE(PF, DV, SV, B) do {                                          \
    int nrow_ = (B) * 64 + lane;                                               \
    DV = mt[(size_t)(B) * 2048 + nrow_];                                       \
    SV = sl[nrow_];                                                            \
    _Pragma("unroll")                                                          \
    for (int pb = 0; pb < 32; ++pb) PF[pb] = mt[(size_t)pb * 2048 + nrow_];    \
} while (0)

#define K5_STEP(PF, DV, SV, B) do {                                           \
    u64 acc_ = 0ull;                                                          \
    _Pragma("unroll")                                                         \
    for (int pb = 0; pb < 32; ++pb) acc_ |= (PF[pb] & kbs[pb]);               \
    int sup_ = ((acc_ != 0ull) || (SV == 0ull)) ? 1 : 0;                      \
    u64 kb_ = 0ull;                                                           \
    u64 bal_ = __ballot(sup_ == 0);                                           \
    while (bal_) {                                                            \
        int j_ = __ffsll((long long)bal_) - 1;                                \
        kb_ |= (1ull << j_);                                                  \
        sup_ |= (int)((DV >> j_) & 1ull);                                     \
        u64 low_ = (j_ < 63) ? ((2ull << j_) - 1ull) : ~0ull;                 \
        bal_ = __ballot(sup_ == 0) & ~low_;   /* low-mask guards NaN self-IoU */ \
    }                                                                         \
    if (lane == 0) {                                                          \
        kbs[(B)] = kb_;                                                       \
        keepmask[m * 32 + (B)] = kb_;                                         \
    }                                                                         \
} while (0)

__global__ __launch_bounds__(64) void k5_nms(const u64* __restrict__ sel,
                                             const u64* __restrict__ maskT,
                                             u64* __restrict__ keepmask) {
    __shared__ u64 kbs[32];
    int m = blockIdx.x;
    int lane = threadIdx.x;                     // 64 threads = 1 wave
    const u64* mt = maskT + (size_t)m * 32 * 2048;
    const u64* sl = sel + (size_t)m * TOPK;
    if (lane < 32) kbs[lane] = 0ull;            // future kb's read as 0
    u64 pfA[32], pfB[32];
    u64 dA = 0ull, sA = 0ull, dB = 0ull, sB = 0ull;
    K5_ISSUE(pfA, dA, sA, 0);                   // step-0 data (pfA & kbs==0 -> no effect)
    #pragma unroll 1
    for (int it = 0; it < 16; ++it) {
        int b0 = 2 * it, b1 = 2 * it + 1;
        K5_ISSUE(pfB, dB, sB, b1);              // prefetch step b1 (overlaps b0's scan)
        K5_STEP(pfA, dA, sA, b0);
        if (b1 < 31) K5_ISSUE(pfA, dA, sA, b1 + 1);  // prefetch step b1+1
        K5_STEP(pfB, dB, sB, b1);
    }
}

// ---------------- K6: gather + write final output ----------------
__global__ void k6_out(const float* __restrict__ pred, const u64* __restrict__ sel,
                       const u64* __restrict__ keepmask, float4* __restrict__ out) {
    int gid = blockIdx.x * 256 + threadIdx.x;   // NIMG*TOPK*4 float4-chunks
    int c4 = gid & 3;
    int r  = (gid >> 2) & (TOPK - 1);
    int m  = gid >> 13;
    float4 o = make_float4(0.f, 0.f, 0.f, 0.f);
    if ((keepmask[m * 32 + (r >> 6)] >> (r & 63)) & 1ull) {
        u64 key = sel[(size_t)m * TOPK + r];
        unsigned idx = 0xFFFFFFFFu - (unsigned)(key & 0xFFFFFFFFull);
        const float4* rv = reinterpret_cast<const float4*>(pred + ((size_t)m * NA + idx) * 16);
        float4 v = rv[c4];
        if (c4 == 0) {
            float hw = __fmul_rn(v.z, 0.5f), hh = __fmul_rn(v.w, 0.5f);
            o = make_float4(__fsub_rn(v.x, hw), __fsub_rn(v.y, hh),
                            __fadd_rn(v.x, hw), __fadd_rn(v.y, hh));
        } else if (c4 == 1) {
            o = make_float4(__uint_as_float((unsigned)(key >> 32)), v.y, v.z, v.w);
        } else if (c4 == 2) {
            o = v;
        } else {
            o = make_float4(v.x, v.y, v.z, 0.f);
        }
    }
    out[gid] = o;
}

// ---------------- launch ----------------
extern "C" void kernel_launch(void* const* d_in, const int* in_sizes, int n_in,
                              void* d_out, int out_size, void* d_ws, size_t ws_size,
                              hipStream_t stream) {
    (void)in_sizes; (void)n_in; (void)out_size; (void)ws_size;
    const float* pred = (const float*)d_in[0];
    char* ws = (char*)d_ws;
    // layout (bytes):
    unsigned* cand32   = (unsigned*)(ws + 0);          // 8*100800*4 = 3,225,600
    u64*      comp     = (u64*)     (ws + 3225600);    // 8*4096*8   =   262,144
    u64*      sel      = (u64*)     (ws + 3487744);    // 8*2048*8   =   131,072
    float4*   boxes    = (float4*)  (ws + 3618816);    // 8*2048*16  =   262,144
    u64*      maskT    = (u64*)     (ws + 3880960);    // 8*32*2048*8= 4,194,304
    u64*      keepmask = (u64*)     (ws + 8075264);    // 8*32*8     =     2,048
    int*      histb    = (int*)     (ws + 8077312);    // 8*99*64*4  =   202,752
    int*      pos      = (int*)     (ws + 8280064);    // 32
    int*      cut      = (int*)     (ws + 8280096);    // 32
    float4*   out      = (float4*)d_out;

    hipLaunchKernelGGL(k1_scan,    dim3(NBLK1, NIMG),            dim3(256),  0, stream, pred, cand32, histb);
    hipLaunchKernelGGL(k2a_cutoff, dim3(NIMG),                   dim3(64),   0, stream, histb, cut, pos);
    hipLaunchKernelGGL(k2b_compact,dim3(NBLK1, NIMG),            dim3(1024), 0, stream, cand32, cut, comp, pos);
    hipLaunchKernelGGL(k2c_rank,   dim3(NIMG),                   dim3(1024), 0, stream, comp, pos, pred, sel, boxes);
    hipLaunchKernelGGL(k4_masks,   dim3(64, NIMG),               dim3(1024), 0, stream, boxes, maskT);
    hipLaunchKernelGGL(k5_nms,     dim3(NIMG),                   dim3(64),   0, stream, sel, maskT, keepmask);
    hipLaunchKernelGGL(k6_out,     dim3(NIMG * TOPK * 4 / 256),  dim3(256),  0, stream, pred, sel, keepmask, out);
}

// Round 12
// 127.172 us; speedup vs baseline: 1.0032x; 1.0032x over previous
//
#include <hip/hip_runtime.h>
#include <stdint.h>

#define NA    100800
#define NIMG  8
#define TOPK  2048
#define NBLK1 99              // ceil(NA / 1024)
typedef unsigned long long u64;

// ---------------- K1: coalesced scan -> dense conf-bits + per-block LDS hist ----------------
__global__ __launch_bounds__(256) void k1_scan(const float* __restrict__ pred,
                                               unsigned* __restrict__ cand32,
                                               int* __restrict__ hist_blocks) {
    __shared__ int lhist[64];
    int t = threadIdx.x;
    int m = blockIdx.y;
    if (t < 64) lhist[t] = 0;
    __syncthreads();
    const float4* p4 = reinterpret_cast<const float4*>(pred + (size_t)m * NA * 16);
    int row0blk = blockIdx.x * 1024;
    for (int pass = 0; pass < 4; ++pass) {
        int row0 = row0blk + pass * 256;
        int i1 = row0 * 4 + 2 * t + 1;
        int i2 = i1 + 512;
        float4 A = make_float4(0.f, 0.f, 0.f, 0.f);
        float4 B = make_float4(0.f, 0.f, 0.f, 0.f);
        if ((i1 >> 2) < NA) A = p4[i1];
        if ((i2 >> 2) < NA) B = p4[i2];
        float aw = __shfl_xor(A.w, 1);          // x15 of row rA (valid on even lanes)
        float bw = __shfl_xor(B.w, 1);          // x15 of row rB
        if (!(t & 1)) {
            int rA = row0 + (t >> 1);
            int rB = rA + 128;
            {
                float obj = A.x, x15 = aw;
                if (rA < NA) {
                    float conf = __fmul_rn(x15, obj);   // exact ref op
                    unsigned cb = 0u;
                    if (obj > 0.5f && conf > 0.5f) {
                        cb = __float_as_uint(conf);
                        atomicAdd(&lhist[min(63, (int)((cb - 0x3F000000u) >> 17))], 1);
                    }
                    cand32[(size_t)m * NA + rA] = cb;
                }
            }
            {
                float obj = B.x, x15 = bw;
                if (rB < NA) {
                    float conf = __fmul_rn(x15, obj);
                    unsigned cb = 0u;
                    if (obj > 0.5f && conf > 0.5f) {
                        cb = __float_as_uint(conf);
                        atomicAdd(&lhist[min(63, (int)((cb - 0x3F000000u) >> 17))], 1);
                    }
                    cand32[(size_t)m * NA + rB] = cb;
                }
            }
        }
    }
    __syncthreads();
    if (t < 64) hist_blocks[((size_t)m * NBLK1 + blockIdx.x) * 64 + t] = lhist[t];
}

// ---------------- K2a: reduce per-block hists + cutoff via suffix-scan (1 wave/image) ----------------
__global__ void k2a_cutoff(const int* __restrict__ hist_blocks, int* __restrict__ cut,
                           int* __restrict__ pos) {
    int m = blockIdx.x;
    int lane = threadIdx.x;                     // 64 threads
    int h = 0;
    #pragma unroll 4
    for (int b = 0; b < NBLK1; ++b)             // coalesced: 64 consecutive ints per b
        h += hist_blocks[((size_t)m * NBLK1 + b) * 64 + lane];
    #pragma unroll
    for (int off = 1; off < 64; off <<= 1) {    // inclusive suffix sum
        int src = lane + off;
        int v = __shfl(h, src < 64 ? src : lane);
        h += (src < 64) ? v : 0;
    }
    int total  = __shfl(h, 0);
    int needed = min(total, TOPK);
    u64 bal = __ballot(h >= needed);
    int cutoff = 63 - __clzll(bal);             // highest bin with suffix >= needed
    if (lane == 0) { cut[m] = cutoff; pos[m] = 0; }
}

// ---------------- K2b: compact bin>=cutoff; ONE atomic per 1024-thread block ----------------
__global__ __launch_bounds__(1024) void k2b_compact(const unsigned* __restrict__ cand32,
                                                    const int* __restrict__ cut,
                                                    u64* __restrict__ comp,
                                                    int* __restrict__ pos) {
    __shared__ int wbase[16];
    __shared__ int sbase;
    int m = blockIdx.y;
    int i = blockIdx.x * 1024 + threadIdx.x;
    int lane = threadIdx.x & 63, wid = threadIdx.x >> 6;
    unsigned cb = (i < NA) ? cand32[(size_t)m * NA + i] : 0u;
    int c = cut[m];
    bool keep = false;
    if (cb) keep = min(63, (int)((cb - 0x3F000000u) >> 17)) >= c;
    u64 bal = __ballot(keep);
    int cnt = __popcll(bal);
    if (lane == 0) wbase[wid] = cnt;
    __syncthreads();
    if (threadIdx.x == 0) {
        int s = 0;
        #pragma unroll
        for (int w = 0; w < 16; ++w) { int v = wbase[w]; wbase[w] = s; s += v; }
        sbase = s ? atomicAdd(&pos[m], s) : 0;
    }
    __syncthreads();
    if (keep) {
        int p = sbase + wbase[wid] + (int)__popcll(bal & ((1ull << lane) - 1ull));
        if (p < 4096)
            comp[(size_t)m * 4096 + p] = ((u64)cb << 32) | (u64)(0xFFFFFFFFu - (unsigned)i);
    }
}

// ---------------- K2c: counting-rank (4096 fine bins) -> sel + staged boxes ----------------
__global__ __launch_bounds__(1024) void k2c_rank(const u64* __restrict__ comp,
                                                 const int* __restrict__ pos,
                                                 const float* __restrict__ pred,
                                                 u64* __restrict__ sel,
                                                 float4* __restrict__ boxes) {
    __shared__ int fcnt[4096];
    __shared__ int fstart[4096];
    __shared__ u64 outb[4096];
    __shared__ int wsum[16];
    int m = blockIdx.x, t = threadIdx.x;
    int M = min(pos[m], 4096);
    const u64* c = comp + (size_t)m * 4096;
    #pragma unroll
    for (int r = 0; r < 4; ++r) { fcnt[t + r * 1024] = 0; outb[t + r * 1024] = 0ull; }
    __syncthreads();
    // phase 1: load keys (strided, coalesced) + fine histogram
    u64 kk[4]; int rb[4];
    #pragma unroll
    for (int r = 0; r < 4; ++r) {
        int i = t + r * 1024;
        kk[r] = 0ull; rb[r] = -1;
        if (i < M) {
            kk[r] = c[i];
            rb[r] = 4095 - (int)(((unsigned)(kk[r] >> 32) - 0x3F000000u) >> 11);
            atomicAdd(&fcnt[rb[r]], 1);
        }
    }
    __syncthreads();
    // phase 2: exclusive prefix sum over 4096 bins (thread t owns bins 4t..4t+3)
    int c0 = fcnt[4 * t], c1 = fcnt[4 * t + 1], c2 = fcnt[4 * t + 2], c3 = fcnt[4 * t + 3];
    int s = c0 + c1 + c2 + c3;
    int lane = t & 63, w = t >> 6;
    int incl = s;
    #pragma unroll
    for (int off = 1; off < 64; off <<= 1) {
        int v = __shfl_up(incl, off);
        if (lane >= off) incl += v;
    }
    if (lane == 63) wsum[w] = incl;
    __syncthreads();
    if (w == 0) {
        int v = (lane < 16) ? wsum[lane] : 0;
        #pragma unroll
        for (int off = 1; off < 16; off <<= 1) {
            int u = __shfl_up(v, off);
            if (lane >= off) v += u;
        }
        if (lane < 16) wsum[lane] = v;     // inclusive wave sums
    }
    __syncthreads();
    int base = (w > 0 ? wsum[w - 1] : 0) + (incl - s);
    fstart[4 * t]     = base;
    fstart[4 * t + 1] = base + c0;
    fstart[4 * t + 2] = base + c0 + c1;
    fstart[4 * t + 3] = base + c0 + c1 + c2;
    __syncthreads();
    // phase 3: scatter (slot order within bin arbitrary; fixed in phase 4)
    #pragma unroll
    for (int r = 0; r < 4; ++r) {
        if (rb[r] >= 0) {
            int old = atomicSub(&fcnt[rb[r]], 1);
            int slot = fstart[rb[r]] + old - 1;
            outb[slot] = kk[r];
        }
    }
    __syncthreads();
    // phase 4: deterministic cleanup — insertion-sort each bin's range desc
    #pragma unroll
    for (int r = 0; r < 4; ++r) {
        int b = t + r * 1024;
        int st = fstart[b];
        int en = (b < 4095) ? fstart[b + 1] : M;
        for (int x = st + 1; x < en; ++x) {
            u64 key = outb[x];
            int y = x - 1;
            while (y >= st && outb[y] < key) { outb[y + 1] = outb[y]; --y; }
            outb[y + 1] = key;
        }
    }
    __syncthreads();
    // phase 5: emit sel + staged xyxy boxes for top-2048
    #pragma unroll
    for (int r = 0; r < 2; ++r) {
        int i = t + r * 1024;
        u64 key = outb[i];
        sel[(size_t)m * TOPK + i] = key;
        float4 b = make_float4(0.f, 0.f, 0.f, 0.f);
        if (key) {
            unsigned idx = 0xFFFFFFFFu - (unsigned)(key & 0xFFFFFFFFull);
            const float4* rv = reinterpret_cast<const float4*>(pred + ((size_t)m * NA + idx) * 16);
            float4 v = rv[0];                   // [xc, yc, w, h]
            float hw = __fmul_rn(v.z, 0.5f), hh = __fmul_rn(v.w, 0.5f);
            b.x = __fsub_rn(v.x, hw);
            b.y = __fsub_rn(v.y, hh);
            b.z = __fadd_rn(v.x, hw);
            b.w = __fadd_rn(v.y, hh);
        }
        boxes[(size_t)m * TOPK + i] = b;
    }
}

// ---------------- K4: 2048x2048 suppression bitmask, TRANSPOSED (iou > 0.45) ----------------
__global__ __launch_bounds__(1024) void k4_masks(const float4* __restrict__ boxes,
                                                 u64* __restrict__ maskT) {
    __shared__ float4 bx[TOPK];
    int m   = blockIdx.y;
    int grp = blockIdx.x;                       // 64 groups of 32 rows
    for (int i = threadIdx.x; i < TOPK; i += 1024)
        bx[i] = boxes[(size_t)m * TOPK + i];
    __syncthreads();

    int il = threadIdx.x & 31;
    int w  = threadIdx.x >> 5;
    int i  = grp * 32 + il;
    float4 b1 = bx[i];
    float a1 = __fmul_rn(__fsub_rn(b1.z, b1.x), __fsub_rn(b1.w, b1.y));
    u64 bits = 0ull;
    #pragma unroll 4
    for (int jj = 0; jj < 64; ++jj) {
        float4 b2 = bx[w * 64 + jj];
        float a2 = __fmul_rn(__fsub_rn(b2.z, b2.x), __fsub_rn(b2.w, b2.y));
        float iw = fmaxf(__fsub_rn(fminf(b1.z, b2.z), fmaxf(b1.x, b2.x)), 0.f);
        float ih = fmaxf(__fsub_rn(fminf(b1.w, b2.w), fmaxf(b1.y, b2.y)), 0.f);
        float inter = __fmul_rn(iw, ih);
        float uni   = __fsub_rn(__fadd_rn(a1, a2), inter);   // (a1+a2)-inter, ref order
        float iou   = __fdiv_rn(inter, uni);
        if (iou > 0.45f) bits |= (1ull << jj);
    }
    maskT[((size_t)m * 32 + w) * 2048 + i] = bits;
}

// ---------------- K5: greedy scan — 3 waves, scalar SGPR scan, lagged ballot agg ----------------
// Wave 0 scans block b each step: alive/kb live in SGPRs (ballots + readfirstlane
// + readlane only), so the per-kept-row iteration is SALU + 2 readlanes.
// Waves 1-2 each own 16 pb-rows in registers (pA[16]/pB[16] named double buffer,
// 64 VGPR — no spill) and compute block b+1's external-suppression word from
// kbs[pb<=b-1] via AND + one ballot (IoU symmetry), written to parity-slot accw.
// The pb=b contribution is wave0's own cfww = ballot(tval & kb). Concurrent reads
// of the in-flight kbs[b] see 0-or-subset (dword-granular LDS) -> benign under OR.
__global__ __launch_bounds__(192) void k5_nms(const u64* __restrict__ sel,
                                              const u64* __restrict__ maskT,
                                              u64* __restrict__ keepmask) {
    __shared__ u64 kbs[32];
    __shared__ u64 accw[2][2];                  // [parity][wave-1], ballot words
    int m = blockIdx.x;
    int t = threadIdx.x;
    int lane = t & 63;
    int wv = t >> 6;                            // 0..2
    const u64* mt = maskT + (size_t)m * 32 * 2048;
    const u64* sl = sel + (size_t)m * TOPK;
    if (t < 32) kbs[t] = 0ull;
    if (t < 4)  accw[t >> 1][t & 1] = 0ull;

    // wave0 scan state (named double buffer)
    u64 dA = 0, sA = 0, tA = 0, dB = 0, sB = 0, tB = 0;
    u64 cfww = 0ull;                            // pb=b-1 -> block b contribution (uniform)
    // update-wave prefetch (named double buffer, 16 rows each)
    u64 pA[16], pB[16];
    int pbb = (wv - 1) * 16;                    // pb base for update waves

#define K5_W0_ISSUE(D, S, T, B) do {                                          \
    D = mt[(size_t)(B) * 2048 + (B) * 64 + lane];                             \
    S = sl[(B) * 64 + lane];                                                  \
    T = ((B) < 31) ? mt[(size_t)(B) * 2048 + ((B) + 1) * 64 + lane] : 0ull;   \
} while (0)

#define K5_UP_ISSUE(P, B) do {                                                \
    _Pragma("unroll")                                                         \
    for (int k = 0; k < 16; ++k)                                              \
        P[k] = mt[(size_t)(pbb + k) * 2048 + (B) * 64 + lane];                \
} while (0)

#define K5_UP_CONSUME(P, B) do {   /* block (B)+1 */                          \
    u64 acc_ = 0ull;                                                          \
    _Pragma("unroll")                                                         \
    for (int k = 0; k < 16; ++k) acc_ |= (P[k] & kbs[pbb + k]);               \
    u64 w_ = __ballot(acc_ != 0ull);                                          \
    if (lane == 0) accw[((B) + 1) & 1][wv - 1] = w_;                          \
} while (0)

#define K5_W0_SCAN(D, S, T, B) do {                                           \
    u64 validw_ = __ballot(S != 0ull);                                        \
    u64 av_ = accw[(B) & 1][0] | accw[(B) & 1][1];                            \
    u64 ext_ = ((u64)__builtin_amdgcn_readfirstlane((unsigned)(av_ >> 32)) << 32) \
             | (u64)(unsigned)__builtin_amdgcn_readfirstlane((unsigned)av_);  \
    u64 alive_ = validw_ & ~ext_ & ~cfww;                                     \
    unsigned dlo_ = (unsigned)(D), dhi_ = (unsigned)((D) >> 32);              \
    u64 kb_ = 0ull;                                                           \
    while (alive_) {                                                          \
        int j_ = __ffsll((long long)alive_) - 1;                              \
        kb_ |= (1ull << j_);                                                  \
        u64 dj_ = ((u64)(unsigned)__builtin_amdgcn_readlane(dhi_, j_) << 32)  \
                |  (u64)(unsigned)__builtin_amdgcn_readlane(dlo_, j_);        \
        alive_ &= ~dj_;                                                       \
        alive_ &= ~(((j_ < 63) ? (2ull << j_) : 0ull) - 1ull);                \
    }                                                                         \
    cfww = ((B) < 31) ? __ballot((T & kb_) != 0ull) : 0ull;                   \
    if (lane == 0) {                                                          \
        kbs[(B)] = kb_;                                                       \
        keepmask[m * 32 + (B)] = kb_;                                         \
    }                                                                         \
} while (0)

    // prologue
    if (wv == 0) {
        K5_W0_ISSUE(dA, sA, tA, 0);
        K5_W0_ISSUE(dB, sB, tB, 1);
    } else {
        K5_UP_ISSUE(pA, 1);                     // consumed at step 0 (block 1)
        K5_UP_ISSUE(pB, 2);                     // consumed at step 1 (block 2)
    }
    __syncthreads();

    #pragma unroll 1
    for (int it = 0; it < 16; ++it) {
        int b0 = 2 * it, b1 = b0 + 1;
        if (wv == 0) {
            K5_W0_SCAN(dA, sA, tA, b0);
            if (b0 + 2 < 32) K5_W0_ISSUE(dA, sA, tA, b0 + 2);
        } else {
            K5_UP_CONSUME(pA, b0);              // block b0+1 (<=31)
            if (b0 + 3 < 32) K5_UP_ISSUE(pA, b0 + 3);
        }
        __syncthreads();
        if (wv == 0) {
            K5_W0_SCAN(dB, sB, tB, b1);
            if (b1 + 2 < 32) K5_W0_ISSUE(dB, sB, tB, b1 + 2);
        } else {
            if (b1 < 31) K5_UP_CONSUME(pB, b1); // block b1+1
            if (b1 + 3 < 32) K5_UP_ISSUE(pB, b1 + 3);
        }
        __syncthreads();
    }
#undef K5_W0_ISSUE
#undef K5_UP_ISSUE
#undef K5_UP_CONSUME
#undef K5_W0_SCAN
}

// ---------------- K6: gather + write final output ----------------
__global__ void k6_out(const float* __restrict__ pred, const u64* __restrict__ sel,
                       const u64* __restrict__ keepmask, float4* __restrict__ out) {
    int gid = blockIdx.x * 256 + threadIdx.x;   // NIMG*TOPK*4 float4-chunks
    int c4 = gid & 3;
    int r  = (gid >> 2) & (TOPK - 1);
    int m  = gid >> 13;
    float4 o = make_float4(0.f, 0.f, 0.f, 0.f);
    if ((keepmask[m * 32 + (r >> 6)] >> (r & 63)) & 1ull) {
        u64 key = sel[(size_t)m * TOPK + r];
        unsigned idx = 0xFFFFFFFFu - (unsigned)(key & 0xFFFFFFFFull);
        const float4* rv = reinterpret_cast<const float4*>(pred + ((size_t)m * NA + idx) * 16);
        float4 v = rv[c4];
        if (c4 == 0) {
            float hw = __fmul_rn(v.z, 0.5f), hh = __fmul_rn(v.w, 0.5f);
            o = make_float4(__fsub_rn(v.x, hw), __fsub_rn(v.y, hh),
                            __fadd_rn(v.x, hw), __fadd_rn(v.y, hh));
        } else if (c4 == 1) {
            o = make_float4(__uint_as_float((unsigned)(key >> 32)), v.y, v.z, v.w);
        } else if (c4 == 2) {
            o = v;
        } else {
            o = make_float4(v.x, v.y, v.z, 0.f);
        }
    }
    out[gid] = o;
}

// ---------------- launch ----------------
extern "C" void kernel_launch(void* const* d_in, const int* in_sizes, int n_in,
                              void* d_out, int out_size, void* d_ws, size_t ws_size,
                              hipStream_t stream) {
    (void)in_sizes; (void)n_in; (void)out_size; (void)ws_size;
    const float* pred = (const float*)d_in[0];
    char* ws = (char*)d_ws;
    // layout (bytes):
    unsigned* cand32   = (unsigned*)(ws + 0);          // 8*100800*4 = 3,225,600
    u64*      comp     = (u64*)     (ws + 3225600);    // 8*4096*8   =   262,144
    u64*      sel      = (u64*)     (ws + 3487744);    // 8*2048*8   =   131,072
    float4*   boxes    = (float4*)  (ws + 3618816);    // 8*2048*16  =   262,144
    u64*      maskT    = (u64*)     (ws + 3880960);    // 8*32*2048*8= 4,194,304
    u64*      keepmask = (u64*)     (ws + 8075264);    // 8*32*8     =     2,048
    int*      histb    = (int*)     (ws + 8077312);    // 8*99*64*4  =   202,752
    int*      pos      = (int*)     (ws + 8280064);    // 32
    int*      cut      = (int*)     (ws + 8280096);    // 32
    float4*   out      = (float4*)d_out;

    hipLaunchKernelGGL(k1_scan,    dim3(NBLK1, NIMG),            dim3(256),  0, stream, pred, cand32, histb);
    hipLaunchKernelGGL(k2a_cutoff, dim3(NIMG),                   dim3(64),   0, stream, histb, cut, pos);
    hipLaunchKernelGGL(k2b_compact,dim3(NBLK1, NIMG),            dim3(1024), 0, stream, cand32, cut, comp, pos);
    hipLaunchKernelGGL(k2c_rank,   dim3(NIMG),                   dim3(1024), 0, stream, comp, pos, pred, sel, boxes);
    hipLaunchKernelGGL(k4_masks,   dim3(64, NIMG),               dim3(1024), 0, stream, boxes, maskT);
    hipLaunchKernelGGL(k5_nms,     dim3(NIMG),                   dim3(192),  0, stream, sel, maskT, keepmask);
    hipLaunchKernelGGL(k6_out,     dim3(NIMG * TOPK * 4 / 256),  dim3(256),  0, stream, pred, sel, keepmask, out);
}

// Round 13
// 121.264 us; speedup vs baseline: 1.0520x; 1.0487x over previous
//
#include <hip/hip_runtime.h>
#include <stdint.h>

#define NA    100800
#define NIMG  8
#define TOPK  2048
#define NBLK1 99              // ceil(NA / 1024)
typedef unsigned long long u64;

// ---------------- K1: coalesced scan -> dense conf-bits + per-block LDS hist ----------------
__global__ __launch_bounds__(256) void k1_scan(const float* __restrict__ pred,
                                               unsigned* __restrict__ cand32,
                                               int* __restrict__ hist_blocks) {
    __shared__ int lhist[64];
    int t = threadIdx.x;
    int m = blockIdx.y;
    if (t < 64) lhist[t] = 0;
    __syncthreads();
    const float4* p4 = reinterpret_cast<const float4*>(pred + (size_t)m * NA * 16);
    int row0blk = blockIdx.x * 1024;
    for (int pass = 0; pass < 4; ++pass) {
        int row0 = row0blk + pass * 256;
        int i1 = row0 * 4 + 2 * t + 1;
        int i2 = i1 + 512;
        float4 A = make_float4(0.f, 0.f, 0.f, 0.f);
        float4 B = make_float4(0.f, 0.f, 0.f, 0.f);
        if ((i1 >> 2) < NA) A = p4[i1];
        if ((i2 >> 2) < NA) B = p4[i2];
        float aw = __shfl_xor(A.w, 1);          // x15 of row rA (valid on even lanes)
        float bw = __shfl_xor(B.w, 1);          // x15 of row rB
        if (!(t & 1)) {
            int rA = row0 + (t >> 1);
            int rB = rA + 128;
            {
                float obj = A.x, x15 = aw;
                if (rA < NA) {
                    float conf = __fmul_rn(x15, obj);   // exact ref op
                    unsigned cb = 0u;
                    if (obj > 0.5f && conf > 0.5f) {
                        cb = __float_as_uint(conf);
                        atomicAdd(&lhist[min(63, (int)((cb - 0x3F000000u) >> 17))], 1);
                    }
                    cand32[(size_t)m * NA + rA] = cb;
                }
            }
            {
                float obj = B.x, x15 = bw;
                if (rB < NA) {
                    float conf = __fmul_rn(x15, obj);
                    unsigned cb = 0u;
                    if (obj > 0.5f && conf > 0.5f) {
                        cb = __float_as_uint(conf);
                        atomicAdd(&lhist[min(63, (int)((cb - 0x3F000000u) >> 17))], 1);
                    }
                    cand32[(size_t)m * NA + rB] = cb;
                }
            }
        }
    }
    __syncthreads();
    if (t < 64) hist_blocks[((size_t)m * NBLK1 + blockIdx.x) * 64 + t] = lhist[t];
}

// ---------------- K2a: reduce per-block hists + cutoff via suffix-scan (1 wave/image) ----------------
__global__ void k2a_cutoff(const int* __restrict__ hist_blocks, int* __restrict__ cut,
                           int* __restrict__ pos) {
    int m = blockIdx.x;
    int lane = threadIdx.x;                     // 64 threads
    int h = 0;
    #pragma unroll 4
    for (int b = 0; b < NBLK1; ++b)             // coalesced: 64 consecutive ints per b
        h += hist_blocks[((size_t)m * NBLK1 + b) * 64 + lane];
    #pragma unroll
    for (int off = 1; off < 64; off <<= 1) {    // inclusive suffix sum
        int src = lane + off;
        int v = __shfl(h, src < 64 ? src : lane);
        h += (src < 64) ? v : 0;
    }
    int total  = __shfl(h, 0);
    int needed = min(total, TOPK);
    u64 bal = __ballot(h >= needed);
    int cutoff = 63 - __clzll(bal);             // highest bin with suffix >= needed
    if (lane == 0) { cut[m] = cutoff; pos[m] = 0; }
}

// ---------------- K2b: compact bin>=cutoff; ONE atomic per 1024-thread block ----------------
__global__ __launch_bounds__(1024) void k2b_compact(const unsigned* __restrict__ cand32,
                                                    const int* __restrict__ cut,
                                                    u64* __restrict__ comp,
                                                    int* __restrict__ pos) {
    __shared__ int wbase[16];
    __shared__ int sbase;
    int m = blockIdx.y;
    int i = blockIdx.x * 1024 + threadIdx.x;
    int lane = threadIdx.x & 63, wid = threadIdx.x >> 6;
    unsigned cb = (i < NA) ? cand32[(size_t)m * NA + i] : 0u;
    int c = cut[m];
    bool keep = false;
    if (cb) keep = min(63, (int)((cb - 0x3F000000u) >> 17)) >= c;
    u64 bal = __ballot(keep);
    int cnt = __popcll(bal);
    if (lane == 0) wbase[wid] = cnt;
    __syncthreads();
    if (threadIdx.x == 0) {
        int s = 0;
        #pragma unroll
        for (int w = 0; w < 16; ++w) { int v = wbase[w]; wbase[w] = s; s += v; }
        sbase = s ? atomicAdd(&pos[m], s) : 0;
    }
    __syncthreads();
    if (keep) {
        int p = sbase + wbase[wid] + (int)__popcll(bal & ((1ull << lane) - 1ull));
        if (p < 4096)
            comp[(size_t)m * 4096 + p] = ((u64)cb << 32) | (u64)(0xFFFFFFFFu - (unsigned)i);
    }
}

// ---------------- K2c: counting-rank (4096 fine bins) -> sel + staged boxes ----------------
__global__ __launch_bounds__(1024) void k2c_rank(const u64* __restrict__ comp,
                                                 const int* __restrict__ pos,
                                                 const float* __restrict__ pred,
                                                 u64* __restrict__ sel,
                                                 float4* __restrict__ boxes) {
    __shared__ int fcnt[4096];
    __shared__ int fstart[4096];
    __shared__ u64 outb[4096];
    __shared__ int wsum[16];
    int m = blockIdx.x, t = threadIdx.x;
    int M = min(pos[m], 4096);
    const u64* c = comp + (size_t)m * 4096;
    #pragma unroll
    for (int r = 0; r < 4; ++r) { fcnt[t + r * 1024] = 0; outb[t + r * 1024] = 0ull; }
    __syncthreads();
    // phase 1: load keys (strided, coalesced) + fine histogram
    u64 kk[4]; int rb[4];
    #pragma unroll
    for (int r = 0; r < 4; ++r) {
        int i = t + r * 1024;
        kk[r] = 0ull; rb[r] = -1;
        if (i < M) {
            kk[r] = c[i];
            rb[r] = 4095 - (int)(((unsigned)(kk[r] >> 32) - 0x3F000000u) >> 11);
            atomicAdd(&fcnt[rb[r]], 1);
        }
    }
    __syncthreads();
    // phase 2: exclusive prefix sum over 4096 bins (thread t owns bins 4t..4t+3)
    int c0 = fcnt[4 * t], c1 = fcnt[4 * t + 1], c2 = fcnt[4 * t + 2], c3 = fcnt[4 * t + 3];
    int s = c0 + c1 + c2 + c3;
    int lane = t & 63, w = t >> 6;
    int incl = s;
    #pragma unroll
    for (int off = 1; off < 64; off <<= 1) {
        int v = __shfl_up(incl, off);
        if (lane >= off) incl += v;
    }
    if (lane == 63) wsum[w] = incl;
    __syncthreads();
    if (w == 0) {
        int v = (lane < 16) ? wsum[lane] : 0;
        #pragma unroll
        for (int off = 1; off < 16; off <<= 1) {
            int u = __shfl_up(v, off);
            if (lane >= off) v += u;
        }
        if (lane < 16) wsum[lane] = v;     // inclusive wave sums
    }
    __syncthreads();
    int base = (w > 0 ? wsum[w - 1] : 0) + (incl - s);
    fstart[4 * t]     = base;
    fstart[4 * t + 1] = base + c0;
    fstart[4 * t + 2] = base + c0 + c1;
    fstart[4 * t + 3] = base + c0 + c1 + c2;
    __syncthreads();
    // phase 3: scatter (slot order within bin arbitrary; fixed in phase 4)
    #pragma unroll
    for (int r = 0; r < 4; ++r) {
        if (rb[r] >= 0) {
            int old = atomicSub(&fcnt[rb[r]], 1);
            int slot = fstart[rb[r]] + old - 1;
            outb[slot] = kk[r];
        }
    }
    __syncthreads();
    // phase 4: deterministic cleanup — insertion-sort each bin's range desc
    #pragma unroll
    for (int r = 0; r < 4; ++r) {
        int b = t + r * 1024;
        int st = fstart[b];
        int en = (b < 4095) ? fstart[b + 1] : M;
        for (int x = st + 1; x < en; ++x) {
            u64 key = outb[x];
            int y = x - 1;
            while (y >= st && outb[y] < key) { outb[y + 1] = outb[y]; --y; }
            outb[y + 1] = key;
        }
    }
    __syncthreads();
    // phase 5: emit sel + staged xyxy boxes for top-2048
    #pragma unroll
    for (int r = 0; r < 2; ++r) {
        int i = t + r * 1024;
        u64 key = outb[i];
        sel[(size_t)m * TOPK + i] = key;
        float4 b = make_float4(0.f, 0.f, 0.f, 0.f);
        if (key) {
            unsigned idx = 0xFFFFFFFFu - (unsigned)(key & 0xFFFFFFFFull);
            const float4* rv = reinterpret_cast<const float4*>(pred + ((size_t)m * NA + idx) * 16);
            float4 v = rv[0];                   // [xc, yc, w, h]
            float hw = __fmul_rn(v.z, 0.5f), hh = __fmul_rn(v.w, 0.5f);
            b.x = __fsub_rn(v.x, hw);
            b.y = __fsub_rn(v.y, hh);
            b.z = __fadd_rn(v.x, hw);
            b.w = __fadd_rn(v.y, hh);
        }
        boxes[(size_t)m * TOPK + i] = b;
    }
}

// ---------------- K4: 2048x2048 suppression bitmask, TRANSPOSED (iou > 0.45) ----------------
__global__ __launch_bounds__(1024) void k4_masks(const float4* __restrict__ boxes,
                                                 u64* __restrict__ maskT) {
    __shared__ float4 bx[TOPK];
    int m   = blockIdx.y;
    int grp = blockIdx.x;                       // 64 groups of 32 rows
    for (int i = threadIdx.x; i < TOPK; i += 1024)
        bx[i] = boxes[(size_t)m * TOPK + i];
    __syncthreads();

    int il = threadIdx.x & 31;
    int w  = threadIdx.x >> 5;
    int i  = grp * 32 + il;
    float4 b1 = bx[i];
    float a1 = __fmul_rn(__fsub_rn(b1.z, b1.x), __fsub_rn(b1.w, b1.y));
    u64 bits = 0ull;
    #pragma unroll 4
    for (int jj = 0; jj < 64; ++jj) {
        float4 b2 = bx[w * 64 + jj];
        float a2 = __fmul_rn(__fsub_rn(b2.z, b2.x), __fsub_rn(b2.w, b2.y));
        float iw = fmaxf(__fsub_rn(fminf(b1.z, b2.z), fmaxf(b1.x, b2.x)), 0.f);
        float ih = fmaxf(__fsub_rn(fminf(b1.w, b2.w), fmaxf(b1.y, b2.y)), 0.f);
        float inter = __fmul_rn(iw, ih);
        float uni   = __fsub_rn(__fadd_rn(a1, a2), inter);   // (a1+a2)-inter, ref order
        float iou   = __fdiv_rn(inter, uni);
        if (iou > 0.45f) bits |= (1ull << jj);
    }
    maskT[((size_t)m * 32 + w) * 2048 + i] = bits;
}

// ---------------- K5: greedy scan (R9-proven structure) + FUSED output write ----------------
// Wave 0 scans block blk (ballot loop); waves 1..15 apply kb[blk-1] to remv
// words blk+1..31 via one ballot each (IoU symmetry); the un-lagged piece
// C(blk,blk+1) is wave0's per-lane cflag. ONE barrier per step. Keep bits are
// stored in LDS (kws) and the same 1024 threads write the final output tail.
__global__ __launch_bounds__(1024) void k5_nms(const u64* __restrict__ sel,
                                               const u64* __restrict__ maskT,
                                               const float* __restrict__ pred,
                                               float4* __restrict__ out) {
    __shared__ u64 remv[32];
    __shared__ u64 kbshare[2];
    __shared__ u64 kws[32];
    int m = blockIdx.x;
    int t = threadIdx.x;
    int lane = t & 63;
    int wv = t >> 6;                            // wave id 0..15
    const u64* mt = maskT + (size_t)m * 32 * 2048;
    if (t < 32) remv[t] = 0ull;
    u64 dval = 0ull, sval = 0ull, tval = 0ull;
    int cflag = 0;                              // row blk*64+lane suppressed by block blk-1's kept
    if (wv == 0) {
        dval = mt[(size_t)0 * 2048 + lane];     // word 0, rows 0..63 (diag)
        sval = sel[(size_t)m * TOPK + lane];
        tval = mt[(size_t)0 * 2048 + 64 + lane];// word 0, rows 64..127 (for C(0,1))
    }
    __syncthreads();
    for (int blk = 0; blk < 32; ++blk) {
        if (wv == 0) {
            // issue next step's loads first (addresses scan-independent)
            u64 dn = 0ull, sn = 0ull, tn = 0ull;
            if (blk < 31) {
                int r = (blk + 1) * 64 + lane;
                dn = mt[(size_t)(blk + 1) * 2048 + r];
                sn = sel[(size_t)m * TOPK + r];
                if (blk < 30) tn = mt[(size_t)(blk + 1) * 2048 + r + 64];
            }
            // ---- scan block blk ----
            u64 ext = remv[blk];
            u64 validw = __ballot(sval != 0ull);
            int sup = (int)((ext >> lane) & 1ull) | cflag
                    | (int)(((~validw) >> lane) & 1ull);
            u64 kb = 0ull;
            u64 bal = __ballot(sup == 0);
            while (bal) {
                int j = __ffsll((long long)bal) - 1;
                kb |= (1ull << j);
                sup |= (int)((dval >> j) & 1ull);   // symmetry: row j suppresses lane?
                u64 low = (j < 63) ? ((2ull << j) - 1ull) : ~0ull;
                bal = __ballot(sup == 0) & ~low;    // low-mask guards NaN self-IoU
            }
            cflag = (blk < 31 && (tval & kb)) ? 1 : 0;  // C(blk, blk+1), per-lane
            if (lane == 0) {
                kbshare[blk & 1] = kb;
                kws[blk] = kb;
            }
            dval = dn; sval = sn; tval = tn;
        } else if (blk >= 1) {
            // ---- lagged update: apply kb[blk-1] to words blk+1..31 ----
            u64 kb = kbshare[(blk - 1) & 1];
            int w1 = blk + wv;                  // blk+1 .. blk+15
            int w2 = blk + 15 + wv;             // blk+16 .. blk+30
            u64 v1 = (w1 < 32) ? mt[(size_t)(blk - 1) * 2048 + w1 * 64 + lane] : 0ull;
            u64 v2 = (w2 < 32) ? mt[(size_t)(blk - 1) * 2048 + w2 * 64 + lane] : 0ull;
            u64 c1 = __ballot((v1 & kb) != 0ull);
            u64 c2 = __ballot((v2 & kb) != 0ull);
            if (w1 < 32 && lane == 0) remv[w1] |= c1;
            if (w2 < 32 && lane == 0) remv[w2] |= c2;
        }
        __syncthreads();
    }
    // ---- fused output write (former k6): 8192 float4-chunks for this image ----
    const u64* sl = sel + (size_t)m * TOPK;
    float4* om = out + (size_t)m * TOPK * 4;
    #pragma unroll
    for (int q = t; q < TOPK * 4; q += 1024) {
        int c4 = q & 3;
        int r  = q >> 2;
        float4 o = make_float4(0.f, 0.f, 0.f, 0.f);
        if ((kws[r >> 6] >> (r & 63)) & 1ull) {
            u64 key = sl[r];
            unsigned idx = 0xFFFFFFFFu - (unsigned)(key & 0xFFFFFFFFull);
            const float4* rv = reinterpret_cast<const float4*>(pred + ((size_t)m * NA + idx) * 16);
            float4 v = rv[c4];
            if (c4 == 0) {
                float hw = __fmul_rn(v.z, 0.5f), hh = __fmul_rn(v.w, 0.5f);
                o = make_float4(__fsub_rn(v.x, hw), __fsub_rn(v.y, hh),
                                __fadd_rn(v.x, hw), __fadd_rn(v.y, hh));
            } else if (c4 == 1) {
                o = make_float4(__uint_as_float((unsigned)(key >> 32)), v.y, v.z, v.w);
            } else if (c4 == 2) {
                o = v;
            } else {
                o = make_float4(v.x, v.y, v.z, 0.f);
            }
        }
        om[q] = o;
    }
}

// ---------------- launch ----------------
extern "C" void kernel_launch(void* const* d_in, const int* in_sizes, int n_in,
                              void* d_out, int out_size, void* d_ws, size_t ws_size,
                              hipStream_t stream) {
    (void)in_sizes; (void)n_in; (void)out_size; (void)ws_size;
    const float* pred = (const float*)d_in[0];
    char* ws = (char*)d_ws;
    // layout (bytes):
    unsigned* cand32   = (unsigned*)(ws + 0);          // 8*100800*4 = 3,225,600
    u64*      comp     = (u64*)     (ws + 3225600);    // 8*4096*8   =   262,144
    u64*      sel      = (u64*)     (ws + 3487744);    // 8*2048*8   =   131,072
    float4*   boxes    = (float4*)  (ws + 3618816);    // 8*2048*16  =   262,144
    u64*      maskT    = (u64*)     (ws + 3880960);    // 8*32*2048*8= 4,194,304
    int*      histb    = (int*)     (ws + 8077312);    // 8*99*64*4  =   202,752
    int*      pos      = (int*)     (ws + 8280064);    // 32
    int*      cut      = (int*)     (ws + 8280096);    // 32
    float4*   out      = (float4*)d_out;

    hipLaunchKernelGGL(k1_scan,    dim3(NBLK1, NIMG),            dim3(256),  0, stream, pred, cand32, histb);
    hipLaunchKernelGGL(k2a_cutoff, dim3(NIMG),                   dim3(64),   0, stream, histb, cut, pos);
    hipLaunchKernelGGL(k2b_compact,dim3(NBLK1, NIMG),            dim3(1024), 0, stream, cand32, cut, comp, pos);
    hipLaunchKernelGGL(k2c_rank,   dim3(NIMG),                   dim3(1024), 0, stream, comp, pos, pred, sel, boxes);
    hipLaunchKernelGGL(k4_masks,   dim3(64, NIMG),               dim3(1024), 0, stream, boxes, maskT);
    hipLaunchKernelGGL(k5_nms,     dim3(NIMG),                   dim3(1024), 0, stream, sel, maskT, pred, out);
}